// Round 10
// baseline (518.347 us; speedup 1.0000x reference)
//
#include <hip/hip_runtime.h>
#include <hip/hip_bf16.h>

// Problem constants (fixed by setup_inputs)
#define T_STEPS 512
#define BATCH   256
#define NN      128                 // n
#define NEMB    1024                // N
#define M_ROWS  (T_STEPS * BATCH)   // 131072
#define NOISE_K 0.13416407864998738f  // sqrt(2/alpha * sigma^2)
#define NB      16                  // batches per producer block
#define CH      4                   // steps per staged noise chunk
#define NSTEP   (T_STEPS - 1)       // 511 update steps
#define NCH     ((NSTEP + CH - 1) / CH)  // 128 chunks (last runs 3 steps)
#define NPROD   16                  // producer blocks
#define NCONS   240                 // consumer blocks

typedef short s16x8 __attribute__((ext_vector_type(8)));
typedef float f32x4 __attribute__((ext_vector_type(4)));
typedef int   s32x2 __attribute__((ext_vector_type(2)));
typedef int   s32x4 __attribute__((ext_vector_type(4)));

union FragU { s32x4 i4; s16x8 s8; };

__device__ __forceinline__ unsigned short f2bf(float f) {
  union { float f; unsigned u; } v; v.f = f;
  unsigned r = v.u + 0x7fffu + ((v.u >> 16) & 1u);  // RNE
  return (unsigned short)(r >> 16);
}
__device__ __forceinline__ float bf2f(unsigned short s) {
  union { unsigned u; float f; } v; v.u = ((unsigned)s) << 16;
  return v.f;
}
// pack two f32 -> one u32 of 2 bf16 (low = first arg), RNE
__device__ __forceinline__ unsigned pkbf(float lo, float hi) {
  __hip_bfloat162 h = __float22bfloat162_rn(float2{lo, hi});
  union { __hip_bfloat162 h; unsigned u; } c; c.h = h; return c.u;
}

// Workgroup barrier, lgkm-only, compiler-fenced on BOTH sides (r5/r6 lesson).
__device__ __forceinline__ void light_barrier() {
  asm volatile("s_waitcnt lgkmcnt(0)" ::: "memory");
  __builtin_amdgcn_s_barrier();
  asm volatile("" ::: "memory");
}

// Memory-side-coherent 8B store (sc0 sc1): bypasses the local XCD L2 so
// consumer blocks on OTHER XCDs see the data once the store completes
// (tracked by vmcnt). Plain stores would strand dirty lines in this XCD's L2.
__device__ __forceinline__ void gstore_b64_sys(void* p, s32x2 d) {
  asm volatile("global_store_dwordx2 %0, %1, off sc0 sc1"
               :: "v"((unsigned long long)(__SIZE_TYPE__)p), "v"(d) : "memory");
}

// LDS union: producer needs 75 KB, consumer 17 KB -> 75 KB/block, so even
// worst-case packing (2 blocks/CU, 150.5 KB <= 160 KB) keeps ALL 256 blocks
// of the grid co-resident: consumer spin-waits can never deadlock.
struct ProdSh {
  char           xld[2][32 * 136];       // x tiles, 2 x 4.25 KB
  float          rns[2][NB * CH * 128];  // noise chunks, 64 KB
  unsigned short uinl[NB * CH * 8];      // (u + K*inp) bf16, 1 KB
};
struct ConsSh {
  unsigned short qt[64 * 128];           // q tile, swizzled, 16 KB
  float          wos[2 * NN];
};
union ShU { ProdSh p; ConsSh c; };

__global__ void init_prog(int* prog) {
  if (threadIdx.x < NPROD) prog[threadIdx.x] = -1;
}

// ---------------------------------------------------------------------------
// Fused kernel. Blocks 0..15: r9 rnn producer (unchanged structure; states
// stores sc1 + progress publication). Blocks 16..255: emb consumer gated by
// prog[] (device-scope atomics). prog lives in states row 0 (t=0 is never
// stored; consumers synthesize zeros for mt<2).
// ---------------------------------------------------------------------------
__global__ __launch_bounds__(256, 1) void fused_kernel(
    const float* __restrict__ u,          // (6, T, B)
    const float* __restrict__ rec_noise,  // (B, T, n)
    const float* __restrict__ inp_noise,  // (B, T, 6)
    const float* __restrict__ W_inp,      // (n, 6)
    const float* __restrict__ W_rec,      // (n, n)
    const float* __restrict__ W_out,      // (2, n)
    const float* __restrict__ q,          // (n, NEMB)
    unsigned short* __restrict__ states,  // (T, B, n) bf16 in d_ws
    int* __restrict__ prog,               // [16], in states row 0
    float* __restrict__ out)
{
  __shared__ ShU sh;
  const int bid = blockIdx.x;
  const int tid = threadIdx.x;

  if (bid < NPROD) {
    // ================= PRODUCER (r9 rnn, 4 cooperating waves) =============
    const int b0 = bid * NB;
    const int wv = tid >> 6;
    const int l  = tid & 63;
    const int lr = l & 15;
    const int lg = l >> 4;

    const int mf0 = wv * 2;
    s16x8 wA[2][5];
    #pragma unroll
    for (int mi = 0; mi < 2; ++mi) {
      const int mf = mf0 + mi;
      const float* wrow = W_rec + (size_t)(mf * 16 + lr) * NN;
      #pragma unroll
      for (int kc = 0; kc < 4; ++kc) {
        f32x4 v0 = *(const f32x4*)(wrow + kc * 32 + lg * 8);
        f32x4 v1 = *(const f32x4*)(wrow + kc * 32 + lg * 8 + 4);
        FragU f;
        f.i4 = s32x4{(int)pkbf(v0.x, v0.y), (int)pkbf(v0.z, v0.w),
                     (int)pkbf(v1.x, v1.y), (int)pkbf(v1.z, v1.w)};
        wA[mi][kc] = f.s8;
      }
      float wi[6] = {0.f, 0.f, 0.f, 0.f, 0.f, 0.f};
      if (lg == 0) {
        #pragma unroll
        for (int j = 0; j < 6; ++j) wi[j] = W_inp[(mf * 16 + lr) * 6 + j];
      }
      FragU f;
      f.i4 = s32x4{(int)pkbf(wi[0], wi[1]), (int)pkbf(wi[2], wi[3]),
                   (int)pkbf(wi[4], wi[5]), 0};
      wA[mi][4] = f.s8;
    }

    for (int i = tid; i < 1088; i += 256) ((int*)&sh.p.xld[0][0])[i] = 0;

    int loff[8];
    #pragma unroll
    for (int s = 0; s < 8; ++s)
      loff[s] = (l >> 5) * 512 + (((l & 31) * 16) ^ (s << 4));

    #pragma unroll
    for (int bb = 0; bb < 4; ++bb) {
      const int b = wv * 4 + bb;
      const char* gb = (const char*)rec_noise +
                       ((size_t)(b0 + b) * T_STEPS + 0) * 512 + loff[b & 7];
      float* db = &sh.p.rns[0][b * 512];
      __builtin_amdgcn_global_load_lds(
          (const __attribute__((address_space(1))) void*)gb,
          (__attribute__((address_space(3))) void*)db, 16, 0, 0);
      __builtin_amdgcn_global_load_lds(
          (const __attribute__((address_space(1))) void*)(gb + 1024),
          (__attribute__((address_space(3))) void*)(db + 256), 16, 0, 0);
    }
    float uu[6], ii[6];
    if (wv == 0) {
      #pragma unroll
      for (int j = 0; j < 6; ++j) {
        uu[j] = u[(size_t)j * (T_STEPS * BATCH) + (size_t)lg * BATCH + b0 + lr];
        ii[j] = inp_noise[((size_t)(b0 + lr) * T_STEPS + lg) * 6 + j];
      }
    }
    asm volatile("s_waitcnt vmcnt(0)" ::: "memory");
    if (wv == 0) {
      *(s32x2*)&sh.p.uinl[(lr * 4 + lg) * 8] =
          s32x2{(int)pkbf(uu[0] + NOISE_K * ii[0], uu[1] + NOISE_K * ii[1]),
                (int)pkbf(uu[2] + NOISE_K * ii[2], uu[3] + NOISE_K * ii[3])};
      *(s32x2*)&sh.p.uinl[(lr * 4 + lg) * 8 + 4] =
          s32x2{(int)pkbf(uu[4] + NOISE_K * ii[4], uu[5] + NOISE_K * ii[5]), 0};
    }
    __syncthreads();

    float xo[2][4];
    #pragma unroll
    for (int mi = 0; mi < 2; ++mi)
      #pragma unroll
      for (int r = 0; r < 4; ++r) xo[mi][r] = 0.f;

    for (int c = 0; c < NCH; ++c) {
      const int  cb   = c & 1;
      const bool more = (c + 1 < NCH);

      if (more) {
        const int t0n = (c + 1) * CH;
        #pragma unroll
        for (int bb = 0; bb < 4; ++bb) {
          const int b = wv * 4 + bb;
          const char* gb = (const char*)rec_noise +
                           ((size_t)(b0 + b) * T_STEPS + t0n) * 512 + loff[b & 7];
          float* db = &sh.p.rns[cb ^ 1][b * 512];
          __builtin_amdgcn_global_load_lds(
              (const __attribute__((address_space(1))) void*)gb,
              (__attribute__((address_space(3))) void*)db, 16, 0, 0);
          __builtin_amdgcn_global_load_lds(
              (const __attribute__((address_space(1))) void*)(gb + 1024),
              (__attribute__((address_space(3))) void*)(db + 256), 16, 0, 0);
        }
        if (wv == 0) {
          const int tb = t0n + lg;
          #pragma unroll
          for (int j = 0; j < 6; ++j) {
            uu[j] = u[(size_t)j * (T_STEPS * BATCH) + (size_t)tb * BATCH + b0 + lr];
            ii[j] = inp_noise[((size_t)(b0 + lr) * T_STEPS + tb) * 6 + j];
          }
        }
      }

      #pragma unroll
      for (int ts = 0; ts < CH; ++ts) {
        const int t = c * CH + ts;
        if (t >= NSTEP) break;
        const int cur = t & 1, nxt = cur ^ 1;

        s16x8 xb[4];
        #pragma unroll
        for (int kc = 0; kc < 4; ++kc) {
          const char* p = sh.p.xld[cur] + (kc * 8 + lg * 2) * 136 + lr * 8;
          s32x2 r1 = *(const s32x2*)p;
          s32x2 r2 = *(const s32x2*)(p + 136);
          FragU f; f.i4 = s32x4{r1.x, r1.y, r2.x, r2.y};
          xb[kc] = f.s8;
        }
        FragU uf; uf.i4 = *(const s32x4*)&sh.p.uinl[(lr * 4 + ts) * 8];
        const s16x8 ub = (lg == 0) ? uf.s8 : s16x8{0, 0, 0, 0, 0, 0, 0, 0};

        unsigned short* srow =
            states + ((size_t)(t + 1) * BATCH + b0 + lr) * NN + lg * 4;

        #pragma unroll
        for (int mi = 0; mi < 2; ++mi) {
          const int mf = mf0 + mi;
          // split 5-deep MFMA chain into 3+2 (two accumulators)
          f32x4 aA = f32x4{0.f, 0.f, 0.f, 0.f};
          f32x4 aB = f32x4{0.f, 0.f, 0.f, 0.f};
          aA = __builtin_amdgcn_mfma_f32_16x16x32_bf16(wA[mi][0], xb[0], aA, 0, 0, 0);
          aB = __builtin_amdgcn_mfma_f32_16x16x32_bf16(wA[mi][1], xb[1], aB, 0, 0, 0);
          aA = __builtin_amdgcn_mfma_f32_16x16x32_bf16(wA[mi][2], xb[2], aA, 0, 0, 0);
          aB = __builtin_amdgcn_mfma_f32_16x16x32_bf16(wA[mi][3], xb[3], aB, 0, 0, 0);
          aA = __builtin_amdgcn_mfma_f32_16x16x32_bf16(wA[mi][4], ub,    aA, 0, 0, 0);
          const f32x4 rn4 = *(const f32x4*)&sh.p.rns[cb][lr * 512 + ts * 128 +
                                 ((mf * 16 + lg * 4) ^ ((lr & 7) << 2))];
          float xn[4];
          #pragma unroll
          for (int r = 0; r < 4; ++r) {
            const float rl = fmaxf(aA[r] + aB[r], 0.f);
            xn[r] = 0.9f * xo[mi][r] + 0.1f * (rl + NOISE_K * rn4[r]);
            xo[mi][r] = xn[r];
          }
          const s32x2 pw{(int)pkbf(xn[0], xn[1]), (int)pkbf(xn[2], xn[3])};
          *(s32x2*)(sh.p.xld[nxt] + (mf * 4 + lg) * 136 + lr * 8) = pw;
          gstore_b64_sys(srow + mf * 16, pw);  // coherent states store
        }
        light_barrier();
      }

      if (more) {
        // keep the 8 newest (this chunk's stores) in flight; everything
        // older -- incl. all stores for rows <= c*CH -- has COMPLETED.
        asm volatile("s_waitcnt vmcnt(8)" ::: "memory");
        if (wv == 0) {
          *(s32x2*)&sh.p.uinl[(lr * 4 + lg) * 8] =
              s32x2{(int)pkbf(uu[0] + NOISE_K * ii[0], uu[1] + NOISE_K * ii[1]),
                    (int)pkbf(uu[2] + NOISE_K * ii[2], uu[3] + NOISE_K * ii[3])};
          *(s32x2*)&sh.p.uinl[(lr * 4 + lg) * 8 + 4] =
              s32x2{(int)pkbf(uu[4] + NOISE_K * ii[4], uu[5] + NOISE_K * ii[5]), 0};
        }
        light_barrier();
        if (tid == 0)
          __hip_atomic_store(&prog[bid], c * CH, __ATOMIC_RELAXED,
                             __HIP_MEMORY_SCOPE_AGENT);
      }
    }

    // final drain: all rows 1..511 complete -> publish 511
    asm volatile("s_waitcnt vmcnt(0)" ::: "memory");
    light_barrier();
    if (tid == 0)
      __hip_atomic_store(&prog[bid], NSTEP, __ATOMIC_RELAXED,
                         __HIP_MEMORY_SCOPE_AGENT);

  } else {
    // ================= CONSUMER (emb + fused W_out), gated ================
    const int k  = bid - NPROD;       // 0..239
    const int jt = k & 15;            // fixed j-tile; q staged once
    const int q0 = k >> 4;            // 0..14 -> mt = q0 + 15*i
    const int w  = tid >> 6;
    const int l  = tid & 63;
    const int lg = l >> 4;
    const int lr = l & 15;

    {
      const int j  = tid & 63;
      const int k0 = tid >> 6;
      #pragma unroll
      for (int kk = k0; kk < 128; kk += 4) {
        float v = q[kk * NEMB + jt * 64 + j];
        int k8 = kk >> 3, e = kk & 7;
        sh.c.qt[j * 128 + ((k8 ^ (j & 7)) << 3) + e] = f2bf(v);
      }
    }
    if (jt == 0) sh.c.wos[tid] = W_out[tid];
    __syncthreads();

    for (int mt = q0; mt < M_ROWS / 128; mt += 15) {
      const int t_need = mt >> 1;

      if (mt >= 2) {
        if (tid == 0) {
          #pragma unroll 1
          for (int g = 0; g < 8; ++g) {
            const int gg = (mt & 1) * 8 + g;
            while (__hip_atomic_load(&prog[gg], __ATOMIC_RELAXED,
                                     __HIP_MEMORY_SCOPE_AGENT) < t_need)
              __builtin_amdgcn_s_sleep(16);
          }
        }
        __syncthreads();  // gate + fence for the whole block
      }

      s16x8 afrag[2][4];
      if (mt >= 2) {
        #pragma unroll
        for (int mf = 0; mf < 2; ++mf) {
          const int m = mt * 128 + w * 32 + mf * 16 + lr;
          const unsigned short* arow = states + (size_t)m * NN;
          #pragma unroll
          for (int kc = 0; kc < 4; ++kc)
            afrag[mf][kc] = *(const s16x8*)(arow + kc * 32 + lg * 8);
        }
      } else {
        #pragma unroll
        for (int mf = 0; mf < 2; ++mf)
          #pragma unroll
          for (int kc = 0; kc < 4; ++kc)
            afrag[mf][kc] = s16x8{0, 0, 0, 0, 0, 0, 0, 0};
      }

      f32x4 acc[2][4] = {};
      #pragma unroll
      for (int kc = 0; kc < 4; ++kc) {
        s16x8 bfrag[4];
        #pragma unroll
        for (int jf = 0; jf < 4; ++jf) {
          const int jl = jf * 16 + lr;
          bfrag[jf] = *(const s16x8*)(sh.c.qt + jl * 128 +
                                      ((((kc << 2) + lg) ^ (jl & 7)) << 3));
        }
        #pragma unroll
        for (int mf = 0; mf < 2; ++mf)
          #pragma unroll
          for (int jf = 0; jf < 4; ++jf)
            acc[mf][jf] = __builtin_amdgcn_mfma_f32_16x16x32_bf16(
                afrag[mf][kc], bfrag[jf], acc[mf][jf], 0, 0, 0);
      }

      if (jt == 0) {
        #pragma unroll
        for (int mf = 0; mf < 2; ++mf) {
          float s0 = 0.f, s1 = 0.f;
          #pragma unroll
          for (int kc = 0; kc < 4; ++kc) {
            const int kb = kc * 32 + lg * 8;
            const s16x8 af = afrag[mf][kc];
            #pragma unroll
            for (int e = 0; e < 8; ++e) {
              const float x = bf2f((unsigned short)af[e]);
              s0 = fmaf(x, sh.c.wos[kb + e], s0);
              s1 = fmaf(x, sh.c.wos[NN + kb + e], s1);
            }
          }
          s0 += __shfl_xor(s0, 16); s0 += __shfl_xor(s0, 32);
          s1 += __shfl_xor(s1, 16); s1 += __shfl_xor(s1, 32);
          if (lg == 0) {
            const long m = (long)mt * 128 + w * 32 + mf * 16 + lr;
            out[(long)1024 * M_ROWS + m] = s0;
            out[(long)1025 * M_ROWS + m] = s1;
          }
        }
      }

      #pragma unroll
      for (int mf = 0; mf < 2; ++mf) {
        const int m = mt * 128 + w * 32 + mf * 16 + lg * 4;
        #pragma unroll
        for (int jf = 0; jf < 4; ++jf) {
          const long j = jt * 64 + jf * 16 + lr;
          *(f32x4*)&out[j * M_ROWS + m] = acc[mf][jf];
        }
      }
    }
  }
}

extern "C" void kernel_launch(void* const* d_in, const int* in_sizes, int n_in,
                              void* d_out, int out_size, void* d_ws, size_t ws_size,
                              hipStream_t stream) {
  const float* u         = (const float*)d_in[0];
  const float* rec_noise = (const float*)d_in[1];
  const float* inp_noise = (const float*)d_in[2];
  const float* W_inp     = (const float*)d_in[3];
  const float* W_rec     = (const float*)d_in[4];
  const float* W_out     = (const float*)d_in[5];
  const float* q         = (const float*)d_in[6];
  float* out = (float*)d_out;
  unsigned short* states = (unsigned short*)d_ws;  // (T, B, n) bf16; row 0 unused
  int* prog = (int*)d_ws;                          // progress flags in row 0

  init_prog<<<dim3(1), dim3(64), 0, stream>>>(prog);
  fused_kernel<<<dim3(NPROD + NCONS), dim3(256), 0, stream>>>(
      u, rec_noise, inp_noise, W_inp, W_rec, W_out, q, states, prog, out);
}

// Round 12
// 459.072 us; speedup vs baseline: 1.1291x; 1.1291x over previous
//
#include <hip/hip_runtime.h>
#include <hip/hip_bf16.h>

// Problem constants (fixed by setup_inputs)
#define T_STEPS 512
#define BATCH   256
#define NN      128                 // n
#define NEMB    1024                // N
#define M_ROWS  (T_STEPS * BATCH)   // 131072
#define NOISE_K 0.13416407864998738f  // sqrt(2/alpha * sigma^2)
#define CH      8                   // steps per staged chunk
#define NCHUNK  (T_STEPS / CH)      // 64 (last chunk runs 7 steps)

typedef short s16x8 __attribute__((ext_vector_type(8)));
typedef float f32x4 __attribute__((ext_vector_type(4)));

__device__ __forceinline__ unsigned short f2bf(float f) {
  union { float f; unsigned u; } v; v.f = f;
  unsigned r = v.u + 0x7fffu + ((v.u >> 16) & 1u);  // RNE
  return (unsigned short)(r >> 16);
}
__device__ __forceinline__ float bf2f(unsigned short s) {
  union { unsigned u; float f; } v; v.u = ((unsigned)s) << 16;
  return v.f;
}
__device__ __forceinline__ float rdlane(float v, int l) {
  return __uint_as_float(__builtin_amdgcn_readlane(__float_as_uint(v), l));
}

// Light workgroup barrier with compiler-level fencing on BOTH sides (r5/r6
// lesson: s_barrier is IntrNoMem). vmcnt deliberately NOT drained.
// This exact helper + producer below passed full replay validation in r7.
__device__ __forceinline__ void light_barrier() {
  asm volatile("s_waitcnt lgkmcnt(0)" ::: "memory");
  __builtin_amdgcn_s_barrier();
  asm volatile("" ::: "memory");
}

// ---------------------------------------------------------------------------
// Kernel 1: leaky-RNN recurrence — BYTE-EXACT r7 version (known-pass).
// One block (128 thr = 2 waves) per batch. Each lane owns one full row
// i = tid: 128 FMAs with x broadcast via readlane->SGPR. x double-buffered
// in LDS (one light barrier per step). Noise staged in 8-step
// double-buffered LDS chunks. states (bf16) -> ws, (T, B, n), row m = t*B+b.
// ---------------------------------------------------------------------------
__global__ __launch_bounds__(128, 1) void rnn_step_kernel(
    const float* __restrict__ u,          // (6, T, B)
    const float* __restrict__ rec_noise,  // (B, T, n)
    const float* __restrict__ inp_noise,  // (B, T, 6)
    const float* __restrict__ W_inp,      // (n, 6)
    const float* __restrict__ W_rec,      // (n, n)
    unsigned short* __restrict__ states)  // (T, B, n) bf16
{
  const int b    = blockIdx.x;
  const int tid  = threadIdx.x;   // 0..127 == row index i
  const int lane = tid & 63;

  __shared__ float xbuf[2][NN];
  __shared__ float rns[2][CH * NN];   // staged rec_noise chunk
  __shared__ float us[2][CH][8];      // staged (u + K*inp_noise) chunk

  // Full W_rec row in registers: 128 floats = 32 x f32x4 (statically indexed)
  const f32x4* wr = (const f32x4*)(W_rec + tid * NN);
  f32x4 w4[32];
  #pragma unroll
  for (int c = 0; c < 32; ++c) w4[c] = wr[c];

  float winp[6];
  #pragma unroll
  for (int j = 0; j < 6; ++j) winp[j] = W_inp[tid * 6 + j];

  const int ts6 = tid / 6, j6 = tid - ts6 * 6;  // (step, input) map for tid<48

  xbuf[0][tid] = 0.f;
  states[b * NN + tid] = 0;  // t=0 state is zero

  // prologue: stage chunk 0 (t = 0..7): 1024 floats by 128 threads (8 each)
  {
    const f32x4* src = (const f32x4*)(rec_noise + (size_t)b * T_STEPS * NN);
    *(f32x4*)&rns[0][tid * 8]     = src[tid * 2];
    *(f32x4*)&rns[0][tid * 8 + 4] = src[tid * 2 + 1];
    if (tid < 48) {
      float uu = u[j6 * (T_STEPS * BATCH) + ts6 * BATCH + b];
      float in = inp_noise[((size_t)b * T_STEPS + ts6) * 6 + j6];
      us[0][ts6][j6] = uu + NOISE_K * in;
    }
  }
  __syncthreads();  // one full drain in the prologue is fine

  float xr = 0.f;  // private copy of x[tid]
  for (int c = 0; c < NCHUNK; ++c) {
    const int cb = c & 1;

    // issue prefetch for chunk c+1 (lands during the 8 steps below)
    f32x4 pf0 = {0.f, 0.f, 0.f, 0.f}, pf1 = {0.f, 0.f, 0.f, 0.f};
    float u_pf = 0.f, in_pf = 0.f;
    if (c < NCHUNK - 1) {
      const f32x4* src =
          (const f32x4*)(rec_noise + ((size_t)b * T_STEPS + (c + 1) * CH) * NN);
      pf0 = src[tid * 2];
      pf1 = src[tid * 2 + 1];
      if (tid < 48) {
        const int tt = (c + 1) * CH + ts6;
        u_pf  = u[j6 * (T_STEPS * BATCH) + tt * BATCH + b];
        in_pf = inp_noise[((size_t)b * T_STEPS + tt) * 6 + j6];
      }
    }

    #pragma unroll
    for (int ts = 0; ts < CH; ++ts) {
      const int t = c * CH + ts;
      if (t > T_STEPS - 2) break;          // uniform: only trims last chunk
      const int cur = ts & 1, nxt = cur ^ 1;  // c*CH even -> parity = ts&1

      // wave-local x copy: lane l holds x[2l], x[2l+1]
      float2 vx = *(const float2*)&xbuf[cur][lane * 2];

      // full-row matvec: x broadcast lane->SGPR, w from VGPR, no LDS reads
      float a0 = 0.f, a1 = 0.f, a2 = 0.f, a3 = 0.f;
      #pragma unroll
      for (int kp = 0; kp < 64; ++kp) {      // k = 2*kp, 2*kp+1
        const float x0 = rdlane(vx.x, kp);
        const float x1 = rdlane(vx.y, kp);
        const float we0 = w4[kp >> 1][(kp & 1) * 2];
        const float we1 = w4[kp >> 1][(kp & 1) * 2 + 1];
        if (kp & 1) { a2 = fmaf(we0, x0, a2); a3 = fmaf(we1, x1, a3); }
        else        { a0 = fmaf(we0, x0, a0); a1 = fmaf(we1, x1, a1); }
      }
      float acc = (a0 + a1) + (a2 + a3);

      float inp = 0.f;
      #pragma unroll
      for (int j = 0; j < 6; ++j) inp = fmaf(winp[j], us[cb][ts][j], inp);

      const float pre = acc + inp;
      const float r   = pre > 0.f ? pre : 0.f;
      const float xn  = 0.9f * xr + 0.1f * (r + NOISE_K * rns[cb][ts * NN + tid]);
      xr = xn;

      xbuf[nxt][tid] = xn;                                  // publish new x
      states[((t + 1) * BATCH + b) * NN + tid] = f2bf(xn);  // no drain below

      light_barrier();  // lgkm-only + fenced both sides (no vmcnt drain)
    }

    // commit prefetched chunk to the other LDS buffer (compiler inserts the
    // vmcnt wait before these ds_writes; loads have had ~8 steps to land)
    if (c < NCHUNK - 1) {
      *(f32x4*)&rns[cb ^ 1][tid * 8]     = pf0;
      *(f32x4*)&rns[cb ^ 1][tid * 8 + 4] = pf1;
      if (tid < 48) us[cb ^ 1][ts6][j6] = u_pf + NOISE_K * in_pf;
      light_barrier();
    }
  }
}

// ---------------------------------------------------------------------------
// Kernel 2: states_embedded = states @ q, written transposed: out[j*M + m],
// plus fused W_out rows (jt==0 blocks only). Identical to r7 EXCEPT the
// epilogue: per-wave LDS transpose (35-float rows: write conflict-free,
// read 2-way = free) + full __syncthreads (hardened vs r11's in-wave fence),
// turning each store instruction into 8 x 128 B full-cacheline segments
// (was 16 x 64 B partials at ~60% write efficiency).
// ---------------------------------------------------------------------------
__global__ __launch_bounds__(256) void emb_kernel(
    const unsigned short* __restrict__ states,  // (M, n) bf16
    const float* __restrict__ q,                // (n, NEMB)
    const float* __restrict__ W_out,            // (2, n)
    float* __restrict__ out)                    // out[j*M + m]
{
  const int jt  = blockIdx.x;   // 0..15 (fast dim -> j-tiles of one m-panel co-resident)
  const int mt  = blockIdx.y;   // 0..1023
  const int tid = threadIdx.x;
  const int w   = tid >> 6;
  const int l   = tid & 63;
  const int lg  = l >> 4;
  const int lr  = l & 15;

  __shared__ unsigned short qt[64 * 128];  // [j][k], swizzled, 16 KB
  __shared__ float tr[4][64 * 35];         // per-wave transpose, 35 KB
  __shared__ float wos[2 * NN];

  // stage q tile -> bf16 LDS (coalesced global reads)
  {
    const int j  = tid & 63;
    const int k0 = tid >> 6;
    #pragma unroll
    for (int kk = k0; kk < 128; kk += 4) {
      float v = q[kk * NEMB + jt * 64 + j];
      int k8 = kk >> 3, e = kk & 7;
      qt[j * 128 + ((k8 ^ (j & 7)) << 3) + e] = f2bf(v);
    }
  }
  if (jt == 0) wos[tid] = W_out[tid];

  // A fragments from global: row = l&15, k-chunk = (l>>4)*8 within each K=32
  s16x8 afrag[2][4];
  #pragma unroll
  for (int mf = 0; mf < 2; ++mf) {
    const int m = mt * 128 + w * 32 + mf * 16 + lr;
    const unsigned short* arow = states + (size_t)m * NN;
    #pragma unroll
    for (int kc = 0; kc < 4; ++kc)
      afrag[mf][kc] = *(const s16x8*)(arow + kc * 32 + lg * 8);
  }
  __syncthreads();

  f32x4 acc[2][4] = {};
  #pragma unroll
  for (int kc = 0; kc < 4; ++kc) {
    s16x8 bfrag[4];
    #pragma unroll
    for (int jf = 0; jf < 4; ++jf) {
      const int jl = jf * 16 + lr;
      bfrag[jf] = *(const s16x8*)(qt + jl * 128 + ((((kc << 2) + lg) ^ (jl & 7)) << 3));
    }
    #pragma unroll
    for (int mf = 0; mf < 2; ++mf)
      #pragma unroll
      for (int jf = 0; jf < 4; ++jf)
        acc[mf][jf] = __builtin_amdgcn_mfma_f32_16x16x32_bf16(
            afrag[mf][kc], bfrag[jf], acc[mf][jf], 0, 0, 0);
  }

  // fused W_out (jt==0 blocks): per-lane partial over its k-chunks, reduce lg
  if (jt == 0) {
    #pragma unroll
    for (int mf = 0; mf < 2; ++mf) {
      float s0 = 0.f, s1 = 0.f;
      #pragma unroll
      for (int kc = 0; kc < 4; ++kc) {
        const int kb = kc * 32 + lg * 8;
        const s16x8 af = afrag[mf][kc];
        #pragma unroll
        for (int e = 0; e < 8; ++e) {
          const float x = bf2f((unsigned short)af[e]);
          s0 = fmaf(x, wos[kb + e], s0);
          s1 = fmaf(x, wos[NN + kb + e], s1);
        }
      }
      s0 += __shfl_xor(s0, 16); s0 += __shfl_xor(s0, 32);
      s1 += __shfl_xor(s1, 16); s1 += __shfl_xor(s1, 32);
      if (lg == 0) {
        const long m = (long)mt * 128 + w * 32 + mf * 16 + lr;
        out[(long)1024 * M_ROWS + m] = s0;
        out[(long)1025 * M_ROWS + m] = s1;
      }
    }
  }

  // per-wave transpose: acc[mf][jf] -> tr[w][j][m_local] (64 rows x 35 floats)
  #pragma unroll
  for (int mf = 0; mf < 2; ++mf) {
    const int ml = mf * 16 + lg * 4;
    #pragma unroll
    for (int jf = 0; jf < 4; ++jf)
      *(f32x4*)&tr[w][(jf * 16 + lr) * 35 + ml] = acc[mf][jf];
  }
  __syncthreads();  // hardened: full barrier (r11 used in-wave fence only)

  // coalesced stores: 8 passes x (8 j-rows x 128 B cacheline segments)
  const int a8 = l >> 3;          // j sub-row
  const int b8 = l & 7;           // 16 B chunk within the 128 B run
  #pragma unroll
  for (int p = 0; p < 8; ++p) {
    const int jr = p * 8 + a8;
    f32x4 v = *(const f32x4*)&tr[w][jr * 35 + b8 * 4];
    *(f32x4*)&out[(long)(jt * 64 + jr) * M_ROWS + mt * 128 + w * 32 + b8 * 4] = v;
  }
}

extern "C" void kernel_launch(void* const* d_in, const int* in_sizes, int n_in,
                              void* d_out, int out_size, void* d_ws, size_t ws_size,
                              hipStream_t stream) {
  const float* u         = (const float*)d_in[0];
  const float* rec_noise = (const float*)d_in[1];
  const float* inp_noise = (const float*)d_in[2];
  const float* W_inp     = (const float*)d_in[3];
  const float* W_rec     = (const float*)d_in[4];
  const float* W_out     = (const float*)d_in[5];
  const float* q         = (const float*)d_in[6];
  float* out = (float*)d_out;
  unsigned short* states = (unsigned short*)d_ws;  // (T, B, n) bf16 = 33.6 MB

  rnn_step_kernel<<<dim3(BATCH), dim3(128), 0, stream>>>(
      u, rec_noise, inp_noise, W_inp, W_rec, states);

  dim3 g2(NEMB / 64, M_ROWS / 128);  // (16, 1024), jt fastest for A-panel L2 reuse
  emb_kernel<<<g2, dim3(256), 0, stream>>>(states, q, W_out, out);
}